// Round 6
// baseline (860.621 us; speedup 1.0000x reference)
//
#include <hip/hip_runtime.h>

#define BK 32
#define NS 512            // K-chunks = grid size; KC = D/NS = 512
#define LROW 40           // ushorts per LDS row: 32 bf16 data + 8 pad (80 B stride)

typedef float f32x4 __attribute__((ext_vector_type(4)));
typedef short s16x8 __attribute__((ext_vector_type(8)));

__device__ __forceinline__ unsigned short f2bf(float f) {
  union { float f; unsigned u; } v; v.f = f;
  return (unsigned short)((v.u + 0x7FFFu + ((v.u >> 16) & 1u)) >> 16);  // RTNE
}

__global__ void __launch_bounds__(64) zero_kernel(float* out) {
  if (threadIdx.x == 0) out[0] = 0.f;
}

// Non-draining barrier: lgkmcnt(0) (my ds ops done) + s_barrier + sched pin.
// Does NOT wait vmcnt -> prefetched global loads stay in flight across it.
__device__ __forceinline__ void barrier_nodrain() {
  asm volatile("s_waitcnt lgkmcnt(0)" ::: "memory");
  __builtin_amdgcn_s_barrier();
  __builtin_amdgcn_sched_barrier(0);
}

// Split-K GEMM: block b owns K-chunk [b*KC,(b+1)*KC), computes full 256x256
// partial into ws + b*65536 (fp16).
// 1024 threads = 16 waves in a 4x4 grid; wave tile 64x64 -> acc = 64 VGPR.
// launch_bounds(1024,8): 2 blocks/CU (8 waves/SIMD), reg cap 256 -> no spill.
// LDS 80 KiB/block: double-buffered [buf][mat][256 rows][LROW].
__global__ void __launch_bounds__(1024, 8)
gemm_kernel(const float* __restrict__ V1, const float* __restrict__ V2,
            _Float16* __restrict__ ws, int D, int KC) {
  __shared__ __align__(16) unsigned short lds[2 * 2 * 256 * LROW];  // 80 KiB

  const int tid  = threadIdx.x;
  const int lane = tid & 63;
  const int wid  = tid >> 6;    // 0..15
  const int wm   = wid >> 2;    // 0..3
  const int wn   = wid & 3;     // 0..3
  const int lr   = lane & 15;
  const int lg   = lane >> 4;

  // staging role: each thread loads 64 B (16 floats) of one row of one matrix
  const int smat  = tid >> 9;         // 0: V1, 1: V2
  const int srow  = (tid >> 1) & 255; // 0..255
  const int shalf = tid & 1;          // which 64 B half of the 128 B row-chunk
  const int nsteps = KC / BK;         // 16

  f32x4 acc[4][4];
#pragma unroll
  for (int a = 0; a < 4; ++a)
#pragma unroll
    for (int b = 0; b < 4; ++b) acc[a][b] = f32x4{0.f, 0.f, 0.f, 0.f};

  const float* src = (smat ? V2 : V1)
      + (size_t)srow * (size_t)D
      + (size_t)blockIdx.x * (size_t)KC + (size_t)shalf * 16;

  float4 s[4];

  auto issue = [&](int t) {
    const float* p = src + (size_t)t * BK;
#pragma unroll
    for (int q = 0; q < 4; ++q) s[q] = *(const float4*)(p + q * 4);
  };
  auto lwrite = [&](int buf) {
    s16x8 w01, w23;
    w01[0] = (short)f2bf(s[0].x); w01[1] = (short)f2bf(s[0].y);
    w01[2] = (short)f2bf(s[0].z); w01[3] = (short)f2bf(s[0].w);
    w01[4] = (short)f2bf(s[1].x); w01[5] = (short)f2bf(s[1].y);
    w01[6] = (short)f2bf(s[1].z); w01[7] = (short)f2bf(s[1].w);
    w23[0] = (short)f2bf(s[2].x); w23[1] = (short)f2bf(s[2].y);
    w23[2] = (short)f2bf(s[2].z); w23[3] = (short)f2bf(s[2].w);
    w23[4] = (short)f2bf(s[3].x); w23[5] = (short)f2bf(s[3].y);
    w23[6] = (short)f2bf(s[3].z); w23[7] = (short)f2bf(s[3].w);
    const int base = ((buf * 2 + smat) * 256 + srow) * LROW + shalf * 16;
    *(s16x8*)&lds[base]     = w01;   // bytes 0..15 of my half (16B aligned)
    *(s16x8*)&lds[base + 8] = w23;   // bytes 16..31
  };

  issue(0);
  lwrite(0);
  if (nsteps > 1) issue(1);
  barrier_nodrain();

  for (int t = 0; t < nsteps; ++t) {
    const int buf = t & 1;

    s16x8 af[4], bfr[4];
#pragma unroll
    for (int f = 0; f < 4; ++f) {
      int r = wm * 64 + f * 16 + lr;
      af[f] = *(const s16x8*)&lds[((buf * 2 + 0) * 256 + r) * LROW + lg * 8];
    }
#pragma unroll
    for (int f = 0; f < 4; ++f) {
      int r = wn * 64 + f * 16 + lr;
      bfr[f] = *(const s16x8*)&lds[((buf * 2 + 1) * 256 + r) * LROW + lg * 8];
    }
#pragma unroll
    for (int mf = 0; mf < 4; ++mf)
#pragma unroll
      for (int nf = 0; nf < 4; ++nf)
        acc[mf][nf] = __builtin_amdgcn_mfma_f32_16x16x32_bf16(af[mf], bfr[nf], acc[mf][nf], 0, 0, 0);

    if (t + 1 < nsteps) {
      lwrite((t + 1) & 1);               // reg-dep waits only loads(t+1)
      if (t + 2 < nsteps) issue(t + 2);  // stays in flight across the barrier
    }
    barrier_nodrain();
  }

  // C/D layout: col = lane&15, row = (lane>>4)*4 + reg. fp16 partial storage
  // (partial ~ N(0,512): |max| ~ 6*sqrt(512) ~ 136 << 65504; zmean err ~1e-6).
  _Float16* Cp = ws + (size_t)blockIdx.x * (256 * 256);
#pragma unroll
  for (int mf = 0; mf < 4; ++mf) {
    int i0 = wm * 64 + mf * 16 + lg * 4;
#pragma unroll
    for (int nf = 0; nf < 4; ++nf) {
      int j = wn * 64 + nf * 16 + lr;
#pragma unroll
      for (int v = 0; v < 4; ++v)
        Cp[(size_t)(i0 + v) * 256 + j] = (_Float16)acc[mf][nf][v];
    }
  }
}

// Sum P fp16 partials, z = dot/D, BCE vs identity labels:
//   diag: softplus(z) - z ; off-diag: softplus(z)
__global__ void __launch_bounds__(256)
loss_kernel(const _Float16* __restrict__ ws, float* __restrict__ out, int P, float invD) {
  const int i = blockIdx.x, j = threadIdx.x;
  const _Float16* base = ws + i * 256 + j;
  float s = 0.f;
#pragma unroll 8
  for (int p = 0; p < P; ++p) s += (float)base[(size_t)p * 65536];
  float z = s * invD;
  float term = log1pf(expf(z)) - (i == j ? z : 0.f);

  __shared__ float red[256];
  red[j] = term;
  __syncthreads();
  for (int st = 128; st > 0; st >>= 1) {
    if (j < st) red[j] += red[j + st];
    __syncthreads();
  }
  if (j == 0) atomicAdd(out, red[0] * (1.f / 65536.f));
}

extern "C" void kernel_launch(void* const* d_in, const int* in_sizes, int n_in,
                              void* d_out, int out_size, void* d_ws, size_t ws_size,
                              hipStream_t stream) {
  const float* V1 = (const float*)d_in[0];
  const float* V2 = (const float*)d_in[1];
  float* out = (float*)d_out;
  _Float16* ws = (_Float16*)d_ws;

  const int N = 256;
  const int D = in_sizes[0] / N;   // 262144

  int ns = NS;                     // 512 partials (fp16) = 64 MB
  while (ns > 1 && (size_t)ns * 65536 * sizeof(_Float16) > ws_size) ns >>= 1;
  const int KC = D / ns;           // 512

  zero_kernel<<<1, 64, 0, stream>>>(out);
  gemm_kernel<<<ns, 1024, 0, stream>>>(V1, V2, ws, D, KC);
  loss_kernel<<<N, 256, 0, stream>>>(ws, out, ns, 1.0f / (float)D);
}

// Round 7
// 155.706 us; speedup vs baseline: 5.5272x; 5.5272x over previous
//
#include <hip/hip_runtime.h>

#define BK 32          // k-elements (fp32) per pipeline stage
#define NCHUNK 256     // grid = K-chunks; KC = D/NCHUNK = 1024
#define THREADS 1024

typedef float f32x4 __attribute__((ext_vector_type(4)));
typedef short s16x8 __attribute__((ext_vector_type(8)));

__device__ __forceinline__ unsigned short f2bf(float f) {
  union { float f; unsigned u; } v; v.f = f;
  return (unsigned short)((v.u + 0x7FFFu + ((v.u >> 16) & 1u)) >> 16);  // RTNE
}

__device__ __forceinline__ s16x8 cvt8(f32x4 a, f32x4 b) {
  s16x8 r;
  r[0]=(short)f2bf(a[0]); r[1]=(short)f2bf(a[1]); r[2]=(short)f2bf(a[2]); r[3]=(short)f2bf(a[3]);
  r[4]=(short)f2bf(b[0]); r[5]=(short)f2bf(b[1]); r[6]=(short)f2bf(b[2]); r[7]=(short)f2bf(b[3]);
  return r;
}

__global__ void __launch_bounds__(64) zero_kernel(float* out) {
  if (threadIdx.x == 0) out[0] = 0.f;
}

// Split-K GEMM: block b owns K-chunk [b*KC,(b+1)*KC), full 256x256 partial
// into ws + b*65536 (fp16). 1024 threads = 16 waves (4x4), wave tile 64x64
// (acc = 64 VGPR; block needs VGPR<=128, no staging regs thanks to
// global_load_lds). fp32 LDS ring, 2 stages x 64 KiB; counted vmcnt(4) so one
// full stage of loads is ALWAYS in flight (queue never empties -> DRAM
// scheduler gets a deep reorder window; R5/R6 spill traffic proved ~4 TB/s
// is achievable with a deep queue on this address pattern).
// Swizzle (rule #21): linear LDS dest; per-lane global source float-offset
// XORed with (row&7)<<2; ds_read applies the same XOR -> bank-conflict-free.
__global__ void __launch_bounds__(THREADS, 4)
gemm_kernel(const float* __restrict__ V1, const float* __restrict__ V2,
            _Float16* __restrict__ ws, int D, int KC) {
  __shared__ __align__(16) float lds[2 * 2 * 256 * BK];  // 128 KiB

  const int tid  = threadIdx.x;
  const int lane = tid & 63;
  const int wid  = tid >> 6;    // 0..15
  const int wm   = wid >> 2;    // 0..3 (M)
  const int wn   = wid & 3;     // 0..3 (N)
  const int lr   = lane & 15;
  const int lg   = lane >> 4;
  const int ns   = KC / BK;     // 32

  // loader role: wave covers a 32-row panel of one matrix; 4 instrs x 8 rows.
  const int mat   = wid >> 3;         // 0: V1, 1: V2
  const int panel = (wid & 7) * 32;
  const int lrow8 = lane >> 3;        // row within an 8-row group
  const int lseg  = lane & 7;         // 16B segment
  const int swz   = (lseg * 4) ^ (lrow8 << 2);   // pre-swizzled source offset

  const float* srcM = mat ? V2 : V1;
  const size_t chunk = (size_t)blockIdx.x * (size_t)KC;
  const float* gsrc[4];
#pragma unroll
  for (int i = 0; i < 4; ++i)
    gsrc[i] = srcM + (size_t)(panel + i * 8 + lrow8) * (size_t)D + chunk + swz;

  auto issue = [&](int t, int s) {
#pragma unroll
    for (int i = 0; i < 4; ++i) {
      const float* g = gsrc[i] + (size_t)t * BK;
      float* l = &lds[(((s * 2 + mat) * 256) + panel + i * 8) * BK];  // wave-uniform
      __builtin_amdgcn_global_load_lds(
          (const __attribute__((address_space(1))) void*)g,
          (__attribute__((address_space(3))) void*)l, 16, 0, 0);
    }
  };

  f32x4 acc[4][4];
#pragma unroll
  for (int a = 0; a < 4; ++a)
#pragma unroll
    for (int b = 0; b < 4; ++b) acc[a][b] = f32x4{0.f, 0.f, 0.f, 0.f};

  issue(0, 0);
  issue(1, 1);     // ns >= 2 always (KC = 1024)

  for (int t = 0; t < ns; ++t) {
    const int s = t & 1;

    // stage t complete chip-wide: my 4 oldest loads done (4 newer stay in
    // flight), then barrier (other waves' loads for stage t also done).
    if (t + 1 < ns) asm volatile("s_waitcnt vmcnt(4)" ::: "memory");
    else            asm volatile("s_waitcnt vmcnt(0)" ::: "memory");
    __builtin_amdgcn_s_barrier();
    __builtin_amdgcn_sched_barrier(0);

    // B fragments (4x): ds_read_b128 pair at swizzled offsets, cvt to bf16
    s16x8 bf[4];
#pragma unroll
    for (int nf = 0; nf < 4; ++nf) {
      int r = wn * 64 + nf * 16 + lr;
      int base = ((s * 2 + 1) * 256 + r) * BK;
      int x = ((r & 7) << 2);
      f32x4 lo = *(const f32x4*)&lds[base + ((lg * 8 + 0) ^ x)];
      f32x4 hi = *(const f32x4*)&lds[base + ((lg * 8 + 4) ^ x)];
      bf[nf] = cvt8(lo, hi);
    }
    // A fragments streamed; MFMA overlaps next frag's ds_read
#pragma unroll
    for (int mf = 0; mf < 4; ++mf) {
      int r = wm * 64 + mf * 16 + lr;
      int base = ((s * 2 + 0) * 256 + r) * BK;
      int x = ((r & 7) << 2);
      f32x4 lo = *(const f32x4*)&lds[base + ((lg * 8 + 0) ^ x)];
      f32x4 hi = *(const f32x4*)&lds[base + ((lg * 8 + 4) ^ x)];
      s16x8 af = cvt8(lo, hi);
#pragma unroll
      for (int nf = 0; nf < 4; ++nf)
        acc[mf][nf] = __builtin_amdgcn_mfma_f32_16x16x32_bf16(af, bf[nf], acc[mf][nf], 0, 0, 0);
    }

    // all waves done READING stage s -> safe to overwrite with stage t+2
    asm volatile("s_waitcnt lgkmcnt(0)" ::: "memory");
    __builtin_amdgcn_s_barrier();
    __builtin_amdgcn_sched_barrier(0);
    if (t + 2 < ns) issue(t + 2, s);
  }

  // C/D layout: col = lane&15, row = (lane>>4)*4 + reg. fp16 partials
  // (|partial| <~ 6*sqrt(1024) ~ 200 << 65504; zmean err ~1e-6 — R5/R6 verified).
  _Float16* Cp = ws + (size_t)blockIdx.x * (256 * 256);
#pragma unroll
  for (int mf = 0; mf < 4; ++mf) {
    int i0 = wm * 64 + mf * 16 + lg * 4;
#pragma unroll
    for (int nf = 0; nf < 4; ++nf) {
      int j = wn * 64 + nf * 16 + lr;
#pragma unroll
      for (int v = 0; v < 4; ++v)
        Cp[(size_t)(i0 + v) * 256 + j] = (_Float16)acc[mf][nf][v];
    }
  }
}

// Sum P fp16 partials, z = dot/D, BCE vs identity labels:
//   diag: softplus(z) - z ; off-diag: softplus(z)
__global__ void __launch_bounds__(256)
loss_kernel(const _Float16* __restrict__ ws, float* __restrict__ out, int P, float invD) {
  const int i = blockIdx.x, j = threadIdx.x;
  const _Float16* base = ws + i * 256 + j;
  float s = 0.f;
#pragma unroll 8
  for (int p = 0; p < P; ++p) s += (float)base[(size_t)p * 65536];
  float z = s * invD;
  float term = log1pf(expf(z)) - (i == j ? z : 0.f);

  __shared__ float red[256];
  red[j] = term;
  __syncthreads();
  for (int st = 128; st > 0; st >>= 1) {
    if (j < st) red[j] += red[j + st];
    __syncthreads();
  }
  if (j == 0) atomicAdd(out, red[0] * (1.f / 65536.f));
}

extern "C" void kernel_launch(void* const* d_in, const int* in_sizes, int n_in,
                              void* d_out, int out_size, void* d_ws, size_t ws_size,
                              hipStream_t stream) {
  const float* V1 = (const float*)d_in[0];
  const float* V2 = (const float*)d_in[1];
  float* out = (float*)d_out;
  _Float16* ws = (_Float16*)d_ws;

  const int N = 256;
  const int D = in_sizes[0] / N;   // 262144
  const int KC = D / NCHUNK;       // 1024

  zero_kernel<<<1, 64, 0, stream>>>(out);
  gemm_kernel<<<NCHUNK, THREADS, 0, stream>>>(V1, V2, ws, D, KC);
  loss_kernel<<<N, 256, 0, stream>>>(ws, out, NCHUNK, 1.0f / (float)D);
}